// Round 1
// baseline (3293.263 us; speedup 1.0000x reference)
//
#include <hip/hip_runtime.h>
#include <cstddef>
#include <cstdint>

// Problem constants (fixed by the reference): N=262144 nodes, H=256, B=4096 graphs.
#define HDIM 256
#define BSEG 4096

__device__ __forceinline__ float leaky(float x) { return x >= 0.f ? x : 0.1f * x; }

// ---------- segment bounds via binary search (batch arrays are sorted) ----------
__global__ void seg_bounds_k(const int* __restrict__ bc, const int* __restrict__ bp,
                             int* __restrict__ sc, int* __restrict__ sp, int n, int nb)
{
    int t = blockIdx.x * blockDim.x + threadIdx.x;
    if (t >= 2 * (nb + 1)) return;
    bool isc = (t <= nb);
    const int* a = isc ? bc : bp;
    int v = isc ? t : t - (nb + 1);
    int lo = 0, hi = n;
    while (lo < hi) { int mid = (lo + hi) >> 1; if (a[mid] < v) lo = mid + 1; else hi = mid; }
    if (isc) sc[t] = lo; else sp[t - (nb + 1)] = lo;
}

// ---------- fp32 tiled GEMM: C = act(A@W [+ A2@W2] [+ bias] [+ rowtab[idx[row]]]) ----------
// A:[M,256] row-major, W:[256,256] row-major (row stride 256), C:[M,256].
// 64x64 tile, BK=16, 256 threads, 4x4 per thread.
template<bool LEAKYACT, bool ROWBIAS, bool DUAL>
__global__ __launch_bounds__(256) void gemm64(
    const float* __restrict__ A, const float* __restrict__ W,
    const float* __restrict__ A2, const float* __restrict__ W2,
    const float* __restrict__ bias, const float* __restrict__ rowtab,
    const int* __restrict__ idx, float* __restrict__ C, int M)
{
    const int K = HDIM, NO = HDIM;
    __shared__ float As [16][68];
    __shared__ float Bs [16][68];
    __shared__ float As2[16][68];
    __shared__ float Bs2[16][68];

    const int tid = threadIdx.x;
    const int tx = tid & 15, ty = tid >> 4;
    const int row0 = blockIdx.x * 64, col0 = blockIdx.y * 64;

    const int lr = tid >> 2;           // 0..63 : A-tile row
    const int lk = (tid & 3) << 2;     // 0,4,8,12 : A-tile k offset
    const int bk = tid >> 4;           // 0..15 : W-tile k
    const int bj = (tid & 15) << 2;    // W-tile col offset

    float acc[4][4] = {};

    for (int k0 = 0; k0 < K; k0 += 16) {
        float4 a4 = *(const float4*)&A[(size_t)(row0 + lr) * K + k0 + lk];
        As[lk + 0][lr] = a4.x; As[lk + 1][lr] = a4.y;
        As[lk + 2][lr] = a4.z; As[lk + 3][lr] = a4.w;
        *(float4*)&Bs[bk][bj] = *(const float4*)&W[(size_t)(k0 + bk) * NO + col0 + bj];
        if (DUAL) {
            float4 c4 = *(const float4*)&A2[(size_t)(row0 + lr) * K + k0 + lk];
            As2[lk + 0][lr] = c4.x; As2[lk + 1][lr] = c4.y;
            As2[lk + 2][lr] = c4.z; As2[lk + 3][lr] = c4.w;
            *(float4*)&Bs2[bk][bj] = *(const float4*)&W2[(size_t)(k0 + bk) * NO + col0 + bj];
        }
        __syncthreads();
        #pragma unroll
        for (int kk = 0; kk < 16; ++kk) {
            float4 av = *(const float4*)&As[kk][ty << 2];
            float4 bv = *(const float4*)&Bs[kk][tx << 2];
            float a_[4] = {av.x, av.y, av.z, av.w};
            float b_[4] = {bv.x, bv.y, bv.z, bv.w};
            #pragma unroll
            for (int i = 0; i < 4; ++i)
                #pragma unroll
                for (int j = 0; j < 4; ++j)
                    acc[i][j] += a_[i] * b_[j];
            if (DUAL) {
                float4 av2 = *(const float4*)&As2[kk][ty << 2];
                float4 bv2 = *(const float4*)&Bs2[kk][tx << 2];
                float c_[4] = {av2.x, av2.y, av2.z, av2.w};
                float d_[4] = {bv2.x, bv2.y, bv2.z, bv2.w};
                #pragma unroll
                for (int i = 0; i < 4; ++i)
                    #pragma unroll
                    for (int j = 0; j < 4; ++j)
                        acc[i][j] += c_[i] * d_[j];
            }
        }
        __syncthreads();
    }

    #pragma unroll
    for (int i = 0; i < 4; ++i) {
        int row = row0 + (ty << 2) + i;
        const float* rt = nullptr;
        if (ROWBIAS) rt = &rowtab[(size_t)idx[row] * NO];
        float vv[4];
        #pragma unroll
        for (int j = 0; j < 4; ++j) {
            int col = col0 + (tx << 2) + j;
            float v = acc[i][j];
            if (bias) v += bias[col];
            if (ROWBIAS) v += rt[col];
            if (LEAKYACT) v = leaky(v);
            vv[j] = v;
        }
        float4 o; o.x = vv[0]; o.y = vv[1]; o.z = vv[2]; o.w = vv[3];
        *(float4*)&C[(size_t)row * NO + col0 + (tx << 2)] = o;
    }
}

// ---------- per-segment column-wise reduce (sum or max), contiguous rows ----------
template<bool ISMAX>
__global__ __launch_bounds__(256) void seg_reduce_k(const float* __restrict__ in,
        const int* __restrict__ starts, float* __restrict__ out)
{
    int b = blockIdx.x, t = threadIdx.x;
    int s = starts[b], e = starts[b + 1];
    float acc = ISMAX ? -INFINITY : 0.f;
    for (int i = s; i < e; ++i) {
        float v = in[(size_t)i * HDIM + t];
        acc = ISMAX ? fmaxf(acc, v) : (acc + v);
    }
    out[(size_t)b * HDIM + t] = acc;
}

// ---------- prealpha GEMV: out[i] = dot(Hd[i,:], w) + b ----------
__global__ __launch_bounds__(256) void gemv_k(const float* __restrict__ Hd,
        const float* __restrict__ w, const float* __restrict__ bptr,
        float* __restrict__ out)
{
    int lane = threadIdx.x & 63, wid = threadIdx.x >> 6;
    int row = blockIdx.x * 4 + wid;
    float4 h  = *(const float4*)&Hd[(size_t)row * HDIM + (lane << 2)];
    float4 ww = *(const float4*)&w[lane << 2];
    float p = h.x * ww.x + h.y * ww.y + h.z * ww.z + h.w * ww.w;
    #pragma unroll
    for (int off = 32; off; off >>= 1) p += __shfl_down(p, off);
    if (lane == 0) out[row] = p + bptr[0];
}

// ---------- scatter softmax over contiguous segments ----------
__global__ __launch_bounds__(64) void seg_softmax_k(const float* __restrict__ pre,
        const int* __restrict__ starts, float* __restrict__ alpha)
{
    int b = blockIdx.x, lane = threadIdx.x;
    int s = starts[b], e = starts[b + 1];
    float m = -INFINITY;
    for (int i = s + lane; i < e; i += 64) m = fmaxf(m, pre[i]);
    #pragma unroll
    for (int off = 32; off; off >>= 1) m = fmaxf(m, __shfl_xor(m, off));
    float sum = 0.f;
    for (int i = s + lane; i < e; i += 64) sum += expf(pre[i] - m);
    #pragma unroll
    for (int off = 32; off; off >>= 1) sum += __shfl_xor(sum, off);
    sum += 1e-6f;
    for (int i = s + lane; i < e; i += 64) alpha[i] = expf(pre[i] - m) / sum;
}

// ---------- vector[b,:] = sum_{i in seg b} raw[i,:] * alpha[i] ----------
__global__ __launch_bounds__(256) void seg_wsum_k(const float* __restrict__ raw,
        const float* __restrict__ alpha, const int* __restrict__ starts,
        float* __restrict__ vec)
{
    int b = blockIdx.x, t = threadIdx.x;
    int s = starts[b], e = starts[b + 1];
    float acc = 0.f;
    for (int i = s; i < e; ++i) acc += raw[(size_t)i * HDIM + t] * alpha[i];
    vec[(size_t)b * HDIM + t] = acc;
}

// ---------- affinity: leaky(vec@W1+b1)@W2 + b2, one block per graph ----------
__global__ __launch_bounds__(256) void affinity_k(const float* __restrict__ vec,
        const float* __restrict__ W1, const float* __restrict__ b1,
        const float* __restrict__ W2, const float* __restrict__ b2,
        float* __restrict__ out)
{
    __shared__ float v[HDIM];
    __shared__ float red[4];
    int b = blockIdx.x, t = threadIdx.x;
    v[t] = vec[(size_t)b * HDIM + t];
    __syncthreads();
    float h = 0.f;
    #pragma unroll 8
    for (int k = 0; k < HDIM; ++k) h += v[k] * W1[(size_t)k * HDIM + t];
    h += b1[t];
    h = leaky(h);
    float p = h * W2[t];
    #pragma unroll
    for (int off = 32; off; off >>= 1) p += __shfl_down(p, off);
    int lane = t & 63, wid = t >> 6;
    if (lane == 0) red[wid] = p;
    __syncthreads();
    if (t == 0) out[b] = red[0] + red[1] + red[2] + red[3] + b2[0];
}

extern "C" void kernel_launch(void* const* d_in, const int* in_sizes, int n_in,
                              void* d_out, int out_size, void* d_ws, size_t ws_size,
                              hipStream_t stream)
{
    const int N = in_sizes[2];      // 262144 (batch_comp length)
    const int H = HDIM;             // 256
    const int B = BSEG;             // 4096

    const float* comp   = (const float*)d_in[0];
    const float* prot   = (const float*)d_in[1];
    const int*   bc     = (const int*)d_in[2];
    const int*   bp     = (const int*)d_in[3];
    const float* c_aff_W = (const float*)d_in[4];
    const float* c_aff_b = (const float*)d_in[5];
    const float* c_sup_W = (const float*)d_in[6];
    const float* c_sup_b = (const float*)d_in[7];
    const float* p_aff_W = (const float*)d_in[8];
    const float* p_aff_b = (const float*)d_in[9];
    const float* raw_W1  = (const float*)d_in[10];
    const float* raw_b1  = (const float*)d_in[11];
    const float* raw_W2  = (const float*)d_in[12];
    const float* raw_b2  = (const float*)d_in[13];
    const float* alpha_W1 = (const float*)d_in[14];
    const float* alpha_b1 = (const float*)d_in[15];
    const float* alpha_W2 = (const float*)d_in[16];
    const float* alpha_b2 = (const float*)d_in[17];
    const float* out_W1  = (const float*)d_in[18];
    const float* out_b1  = (const float*)d_in[19];
    const float* out_W2  = (const float*)d_in[20];
    const float* out_b2  = (const float*)d_in[21];

    // ---- workspace layout (aliased) ----
    const size_t NBIG = (size_t)N * H;          // elements of one [N,H] buffer
    const size_t SSEG = (size_t)B * H;          // elements of one [B,H] buffer
    float* bufA = (float*)d_ws;                 // comp_emb -> raw
    float* bufB = bufA + NBIG;                  // csup -> hid_raw
    float* bufC = bufB + NBIG;                  // prot_emb -> hid_alpha
    float* supe = bufC + NBIG;
    float* pool = supe + SSEG;
    float* gr   = pool + SSEG;                  // Gsum_raw  = supe@W1b + pool@W1c + b1
    float* ga   = gr + SSEG;                    // Gsum_alpha
    float* pre  = ga + SSEG;                    // prealpha [N]
    int*   sc   = (int*)(pre + N);              // comp segment starts [B+1]
    int*   sp   = sc + (B + 1);                 // prot segment starts [B+1]
    size_t need_bytes = ((size_t)(sp + (B + 1)) - (size_t)d_ws);
    if (ws_size < need_bytes) return;           // insufficient scratch: bail (bench will flag)

    // outputs: [vector B*H][alpha N][affinity B]
    float* out_vec   = (float*)d_out;
    float* out_alpha = out_vec + SSEG;
    float* out_aff   = out_alpha + N;

    dim3 blk(256);
    dim3 gN(N / 64, H / 64);
    dim3 gB(B / 64, H / 64);

    // 1. segment bounds
    seg_bounds_k<<<(2 * (B + 1) + 255) / 256, blk, 0, stream>>>(bc, bp, sc, sp, N, B);
    // 2-4. the three big leaky GEMMs
    gemm64<true, false, false><<<gN, blk, 0, stream>>>(comp, c_aff_W, nullptr, nullptr,
        c_aff_b, nullptr, nullptr, bufA, N);
    gemm64<true, false, false><<<gN, blk, 0, stream>>>(comp, c_sup_W, nullptr, nullptr,
        c_sup_b, nullptr, nullptr, bufB, N);
    gemm64<true, false, false><<<gN, blk, 0, stream>>>(prot, p_aff_W, nullptr, nullptr,
        p_aff_b, nullptr, nullptr, bufC, N);
    // 5-6. segment pools
    seg_reduce_k<false><<<B, blk, 0, stream>>>(bufB, sc, supe);
    seg_reduce_k<true ><<<B, blk, 0, stream>>>(bufC, sp, pool);
    // 7-8. small dual GEMMs on [B,H]: G = supe@W1[256:512] + pool@W1[512:768] + b1
    gemm64<false, false, true><<<gB, blk, 0, stream>>>(supe, raw_W1 + H * H, pool,
        raw_W1 + 2 * H * H, raw_b1, nullptr, nullptr, gr, B);
    gemm64<false, false, true><<<gB, blk, 0, stream>>>(supe, alpha_W1 + H * H, pool,
        alpha_W1 + 2 * H * H, alpha_b1, nullptr, nullptr, ga, B);
    // 9-10. hid_raw / hid_alpha: leaky(comp_emb@W1[0:256] + G[bc[row]])
    gemm64<true, true, false><<<gN, blk, 0, stream>>>(bufA, raw_W1, nullptr, nullptr,
        nullptr, gr, bc, bufB, N);
    gemm64<true, true, false><<<gN, blk, 0, stream>>>(bufA, alpha_W1, nullptr, nullptr,
        nullptr, ga, bc, bufC, N);
    // 11. raw = hid_raw@raw_W2 + raw_b2  (into bufA; comp_emb dead)
    gemm64<false, false, false><<<gN, blk, 0, stream>>>(bufB, raw_W2, nullptr, nullptr,
        raw_b2, nullptr, nullptr, bufA, N);
    // 12. prealpha = hid_alpha @ alpha_W2 + alpha_b2
    gemv_k<<<N / 4, blk, 0, stream>>>(bufC, alpha_W2, alpha_b2, pre);
    // 13. scatter softmax -> alpha output
    seg_softmax_k<<<B, dim3(64), 0, stream>>>(pre, sc, out_alpha);
    // 14. vector = seg_sum(raw * alpha) -> output
    seg_wsum_k<<<B, blk, 0, stream>>>(bufA, out_alpha, sc, out_vec);
    // 15. affinity head -> output
    affinity_k<<<B, blk, 0, stream>>>(out_vec, out_W1, out_b1, out_W2, out_b2, out_aff);
}

// Round 2
// 1135.713 us; speedup vs baseline: 2.8997x; 2.8997x over previous
//
#include <hip/hip_runtime.h>
#include <cstddef>
#include <cstdint>

#define HDIM 256
#define BSEG 4096

typedef __bf16 bf16x8 __attribute__((ext_vector_type(8)));
typedef float f32x4 __attribute__((ext_vector_type(4)));

__device__ __forceinline__ float leaky(float x) { return x >= 0.f ? x : 0.1f * x; }

__device__ __forceinline__ float bf2f(ushort u) {
    return __builtin_bit_cast(float, (uint32_t)u << 16);
}
__device__ __forceinline__ ushort f2bf(float f) {  // RNE
    uint32_t x = __builtin_bit_cast(uint32_t, f);
    return (ushort)((x + 0x7fffu + ((x >> 16) & 1u)) >> 16);
}

// async global->LDS, 16 bytes per lane
__device__ __forceinline__ void gld16(const ushort* g, ushort* lds) {
    __builtin_amdgcn_global_load_lds(
        (const __attribute__((address_space(1))) uint32_t*)g,
        (__attribute__((address_space(3))) uint32_t*)lds, 16, 0, 0);
}

// ---------- segment bounds (batch arrays sorted) ----------
__global__ void seg_bounds_k(const int* __restrict__ bc, const int* __restrict__ bp,
                             int* __restrict__ sc, int* __restrict__ sp, int n, int nb)
{
    int t = blockIdx.x * blockDim.x + threadIdx.x;
    if (t >= 2 * (nb + 1)) return;
    bool isc = (t <= nb);
    const int* a = isc ? bc : bp;
    int v = isc ? t : t - (nb + 1);
    int lo = 0, hi = n;
    while (lo < hi) { int mid = (lo + hi) >> 1; if (a[mid] < v) lo = mid + 1; else hi = mid; }
    if (isc) sc[t] = lo; else sp[t - (nb + 1)] = lo;
}

// ---------- fp32 -> bf16 cast (vectorized) ----------
__global__ __launch_bounds__(256) void cast_bf_k(const float* __restrict__ in,
        ushort* __restrict__ out, long n4)
{
    long i = (long)blockIdx.x * blockDim.x + threadIdx.x;
    long stride = (long)gridDim.x * blockDim.x;
    for (; i < n4; i += stride) {
        float4 v = ((const float4*)in)[i];
        ushort4 o; o.x = f2bf(v.x); o.y = f2bf(v.y); o.z = f2bf(v.z); o.w = f2bf(v.w);
        ((ushort4*)out)[i] = o;
    }
}

// ---------- weight transpose + cast: WT[c*K + r] = bf16(W[r*NO + c]) ----------
__global__ __launch_bounds__(256) void wt_cast_k(const float* __restrict__ W,
        ushort* __restrict__ WT, int K, int NO)
{
    int i = blockIdx.x * 256 + threadIdx.x;
    if (i >= K * NO) return;
    int r = i / NO, c = i % NO;
    WT[(size_t)c * K + r] = f2bf(W[i]);
}

// ---------- bf16 MFMA GEMM ----------
// A:[M,256] bf16 row-major. BT:[NOtot,256] bf16 (weights pre-transposed).
// Out columns split in halves of 256: half h uses bias_h / rt_h / out_h.
// C = act(A@BT^T + bias + rt[idx[row]]) written as bf16 [M,256] per half.
// 128x128 tile, BK=32, 256 threads (4 waves, 2x2), 4x4 16x16 frags per wave.
template<bool LEAKYACT, bool ROWBIAS>
__global__ __launch_bounds__(256) void mgemm(
    const ushort* __restrict__ A, const ushort* __restrict__ BT,
    const float* __restrict__ bias0, const float* __restrict__ bias1,
    const float* __restrict__ rt0, const float* __restrict__ rt1,
    const int* __restrict__ idx,
    ushort* __restrict__ out0, ushort* __restrict__ out1)
{
    __shared__ __attribute__((aligned(16))) ushort As[128 * 32];
    __shared__ __attribute__((aligned(16))) ushort Bs[128 * 32];

    const int tid = threadIdx.x;
    const int row0 = blockIdx.x * 128;
    const int col0 = blockIdx.y * 128;

    const int w = tid >> 6, l = tid & 63;
    const int wr = (w >> 1) * 64, wc = (w & 1) * 64;
    const int lr = l & 15, lk = (l >> 4) << 3;

    const int tq = tid >> 2;           // staging row 0..63
    const int tb = (tid & 3) << 3;     // staging k-elem offset 0,8,16,24

    f32x4 acc[4][4] = {};

    const ushort* Ab = A + (size_t)(row0 + tq) * HDIM + tb;
    const ushort* Bb = BT + (size_t)(col0 + tq) * HDIM + tb;

    for (int k0 = 0; k0 < HDIM; k0 += 32) {
        gld16(Ab + k0, &As[tid * 8]);
        gld16(Ab + 64 * HDIM + k0, &As[2048 + tid * 8]);
        gld16(Bb + k0, &Bs[tid * 8]);
        gld16(Bb + 64 * HDIM + k0, &Bs[2048 + tid * 8]);
        __syncthreads();

        bf16x8 af[4], bfv[4];
        #pragma unroll
        for (int m = 0; m < 4; ++m)
            af[m] = *(const bf16x8*)&As[(wr + m * 16 + lr) * 32 + lk];
        #pragma unroll
        for (int n = 0; n < 4; ++n)
            bfv[n] = *(const bf16x8*)&Bs[(wc + n * 16 + lr) * 32 + lk];
        #pragma unroll
        for (int m = 0; m < 4; ++m)
            #pragma unroll
            for (int n = 0; n < 4; ++n)
                acc[m][n] = __builtin_amdgcn_mfma_f32_16x16x32_bf16(af[m], bfv[n], acc[m][n], 0, 0, 0);
        __syncthreads();
    }

    const int half = col0 >> 8;  // block-uniform (BN=128)
    const float* bias = half ? bias1 : bias0;
    const float* rtab = half ? rt1 : rt0;
    ushort* outp = half ? out1 : out0;
    const int oc0 = (col0 & 255) + wc;

    #pragma unroll
    for (int m = 0; m < 4; ++m) {
        #pragma unroll
        for (int e = 0; e < 4; ++e) {
            int row = row0 + wr + m * 16 + ((l >> 4) << 2) + e;
            const float* rrow = nullptr;
            if (ROWBIAS) rrow = rtab + (size_t)idx[row] * HDIM;
            #pragma unroll
            for (int n = 0; n < 4; ++n) {
                int c = oc0 + n * 16 + lr;
                float v = acc[m][n][e];
                if (bias) v += bias[c];
                if (ROWBIAS) v += rrow[c];
                if (LEAKYACT) v = leaky(v);
                outp[(size_t)row * HDIM + c] = f2bf(v);
            }
        }
    }
}

// ---------- fp32 tiled GEMM (kept for the small dual [B,H] GEMMs) ----------
template<bool LEAKYACT, bool ROWBIAS, bool DUAL>
__global__ __launch_bounds__(256) void gemm64(
    const float* __restrict__ A, const float* __restrict__ W,
    const float* __restrict__ A2, const float* __restrict__ W2,
    const float* __restrict__ bias, const float* __restrict__ rowtab,
    const int* __restrict__ idx, float* __restrict__ C, int M)
{
    const int K = HDIM, NO = HDIM;
    __shared__ float As [16][68];
    __shared__ float Bs [16][68];
    __shared__ float As2[16][68];
    __shared__ float Bs2[16][68];

    const int tid = threadIdx.x;
    const int tx = tid & 15, ty = tid >> 4;
    const int row0 = blockIdx.x * 64, col0 = blockIdx.y * 64;

    const int lr = tid >> 2;
    const int lk = (tid & 3) << 2;
    const int bk = tid >> 4;
    const int bj = (tid & 15) << 2;

    float acc[4][4] = {};

    for (int k0 = 0; k0 < K; k0 += 16) {
        float4 a4 = *(const float4*)&A[(size_t)(row0 + lr) * K + k0 + lk];
        As[lk + 0][lr] = a4.x; As[lk + 1][lr] = a4.y;
        As[lk + 2][lr] = a4.z; As[lk + 3][lr] = a4.w;
        *(float4*)&Bs[bk][bj] = *(const float4*)&W[(size_t)(k0 + bk) * NO + col0 + bj];
        if (DUAL) {
            float4 c4 = *(const float4*)&A2[(size_t)(row0 + lr) * K + k0 + lk];
            As2[lk + 0][lr] = c4.x; As2[lk + 1][lr] = c4.y;
            As2[lk + 2][lr] = c4.z; As2[lk + 3][lr] = c4.w;
            *(float4*)&Bs2[bk][bj] = *(const float4*)&W2[(size_t)(k0 + bk) * NO + col0 + bj];
        }
        __syncthreads();
        #pragma unroll
        for (int kk = 0; kk < 16; ++kk) {
            float4 av = *(const float4*)&As[kk][ty << 2];
            float4 bv = *(const float4*)&Bs[kk][tx << 2];
            float a_[4] = {av.x, av.y, av.z, av.w};
            float b_[4] = {bv.x, bv.y, bv.z, bv.w};
            #pragma unroll
            for (int i = 0; i < 4; ++i)
                #pragma unroll
                for (int j = 0; j < 4; ++j)
                    acc[i][j] += a_[i] * b_[j];
            if (DUAL) {
                float4 av2 = *(const float4*)&As2[kk][ty << 2];
                float4 bv2 = *(const float4*)&Bs2[kk][tx << 2];
                float c_[4] = {av2.x, av2.y, av2.z, av2.w};
                float d_[4] = {bv2.x, bv2.y, bv2.z, bv2.w};
                #pragma unroll
                for (int i = 0; i < 4; ++i)
                    #pragma unroll
                    for (int j = 0; j < 4; ++j)
                        acc[i][j] += c_[i] * d_[j];
            }
        }
        __syncthreads();
    }

    #pragma unroll
    for (int i = 0; i < 4; ++i) {
        int row = row0 + (ty << 2) + i;
        const float* rt = nullptr;
        if (ROWBIAS) rt = &rowtab[(size_t)idx[row] * NO];
        float vv[4];
        #pragma unroll
        for (int j = 0; j < 4; ++j) {
            int col = col0 + (tx << 2) + j;
            float v = acc[i][j];
            if (bias) v += bias[col];
            if (ROWBIAS) v += rt[col];
            if (LEAKYACT) v = leaky(v);
            vv[j] = v;
        }
        float4 o; o.x = vv[0]; o.y = vv[1]; o.z = vv[2]; o.w = vv[3];
        *(float4*)&C[(size_t)row * NO + col0 + (tx << 2)] = o;
    }
}

// ---------- per-segment column reduce from bf16 input (sum or max) ----------
template<bool ISMAX>
__global__ __launch_bounds__(256) void seg_reduce_bf(const ushort* __restrict__ in,
        const int* __restrict__ starts, float* __restrict__ out)
{
    __shared__ float part[4][HDIM];
    int b = blockIdx.x, tid = threadIdx.x;
    int wid = tid >> 6, lane = tid & 63;
    int s = starts[b], e = starts[b + 1];
    float a0 = ISMAX ? -INFINITY : 0.f, a1 = a0, a2 = a0, a3 = a0;
    for (int i = s + wid; i < e; i += 4) {
        ushort4 v = *(const ushort4*)&in[(size_t)i * HDIM + lane * 4];
        float f0 = bf2f(v.x), f1 = bf2f(v.y), f2 = bf2f(v.z), f3 = bf2f(v.w);
        if (ISMAX) { a0 = fmaxf(a0, f0); a1 = fmaxf(a1, f1); a2 = fmaxf(a2, f2); a3 = fmaxf(a3, f3); }
        else       { a0 += f0; a1 += f1; a2 += f2; a3 += f3; }
    }
    part[wid][lane * 4 + 0] = a0; part[wid][lane * 4 + 1] = a1;
    part[wid][lane * 4 + 2] = a2; part[wid][lane * 4 + 3] = a3;
    __syncthreads();
    float r = ISMAX ? fmaxf(fmaxf(part[0][tid], part[1][tid]), fmaxf(part[2][tid], part[3][tid]))
                    : (part[0][tid] + part[1][tid] + part[2][tid] + part[3][tid]);
    out[(size_t)b * HDIM + tid] = r;
}

// ---------- prealpha GEMV from bf16 hidden ----------
__global__ __launch_bounds__(256) void gemv_bf(const ushort* __restrict__ Hd,
        const float* __restrict__ w, const float* __restrict__ bptr,
        float* __restrict__ out)
{
    int lane = threadIdx.x & 63, wid = threadIdx.x >> 6;
    int row = blockIdx.x * 4 + wid;
    ushort4 h4 = *(const ushort4*)&Hd[(size_t)row * HDIM + lane * 4];
    float4 wv = *(const float4*)&w[lane * 4];
    float p = bf2f(h4.x) * wv.x + bf2f(h4.y) * wv.y + bf2f(h4.z) * wv.z + bf2f(h4.w) * wv.w;
    #pragma unroll
    for (int off = 32; off; off >>= 1) p += __shfl_down(p, off);
    if (lane == 0) out[row] = p + bptr[0];
}

// ---------- scatter softmax over contiguous segments ----------
__global__ __launch_bounds__(64) void seg_softmax_k(const float* __restrict__ pre,
        const int* __restrict__ starts, float* __restrict__ alpha)
{
    int b = blockIdx.x, lane = threadIdx.x;
    int s = starts[b], e = starts[b + 1];
    float m = -INFINITY;
    for (int i = s + lane; i < e; i += 64) m = fmaxf(m, pre[i]);
    #pragma unroll
    for (int off = 32; off; off >>= 1) m = fmaxf(m, __shfl_xor(m, off));
    float sum = 0.f;
    for (int i = s + lane; i < e; i += 64) sum += expf(pre[i] - m);
    #pragma unroll
    for (int off = 32; off; off >>= 1) sum += __shfl_xor(sum, off);
    sum += 1e-6f;
    for (int i = s + lane; i < e; i += 64) alpha[i] = expf(pre[i] - m) / sum;
}

// ---------- vector[b,:] = sum raw[i,:]*alpha[i], raw in bf16 ----------
__global__ __launch_bounds__(256) void seg_wsum_bf(const ushort* __restrict__ raw,
        const float* __restrict__ alpha, const int* __restrict__ starts,
        float* __restrict__ vec)
{
    __shared__ float part[4][HDIM];
    int b = blockIdx.x, tid = threadIdx.x;
    int wid = tid >> 6, lane = tid & 63;
    int s = starts[b], e = starts[b + 1];
    float a0 = 0.f, a1 = 0.f, a2 = 0.f, a3 = 0.f;
    for (int i = s + wid; i < e; i += 4) {
        float al = alpha[i];
        ushort4 v = *(const ushort4*)&raw[(size_t)i * HDIM + lane * 4];
        a0 += bf2f(v.x) * al; a1 += bf2f(v.y) * al; a2 += bf2f(v.z) * al; a3 += bf2f(v.w) * al;
    }
    part[wid][lane * 4 + 0] = a0; part[wid][lane * 4 + 1] = a1;
    part[wid][lane * 4 + 2] = a2; part[wid][lane * 4 + 3] = a3;
    __syncthreads();
    vec[(size_t)b * HDIM + tid] = part[0][tid] + part[1][tid] + part[2][tid] + part[3][tid];
}

// ---------- affinity head ----------
__global__ __launch_bounds__(256) void affinity_k(const float* __restrict__ vec,
        const float* __restrict__ W1, const float* __restrict__ b1,
        const float* __restrict__ W2, const float* __restrict__ b2,
        float* __restrict__ out)
{
    __shared__ float v[HDIM];
    __shared__ float red[4];
    int b = blockIdx.x, t = threadIdx.x;
    v[t] = vec[(size_t)b * HDIM + t];
    __syncthreads();
    float h = 0.f;
    #pragma unroll 8
    for (int k = 0; k < HDIM; ++k) h += v[k] * W1[(size_t)k * HDIM + t];
    h += b1[t];
    h = leaky(h);
    float p = h * W2[t];
    #pragma unroll
    for (int off = 32; off; off >>= 1) p += __shfl_down(p, off);
    int lane = t & 63, wid = t >> 6;
    if (lane == 0) red[wid] = p;
    __syncthreads();
    if (t == 0) out[b] = red[0] + red[1] + red[2] + red[3] + b2[0];
}

extern "C" void kernel_launch(void* const* d_in, const int* in_sizes, int n_in,
                              void* d_out, int out_size, void* d_ws, size_t ws_size,
                              hipStream_t stream)
{
    const int N = in_sizes[2];
    const int H = HDIM;
    const int B = BSEG;

    const float* comp   = (const float*)d_in[0];
    const float* prot   = (const float*)d_in[1];
    const int*   bc     = (const int*)d_in[2];
    const int*   bp     = (const int*)d_in[3];
    const float* c_aff_W = (const float*)d_in[4];
    const float* c_aff_b = (const float*)d_in[5];
    const float* c_sup_W = (const float*)d_in[6];
    const float* c_sup_b = (const float*)d_in[7];
    const float* p_aff_W = (const float*)d_in[8];
    const float* p_aff_b = (const float*)d_in[9];
    const float* raw_W1  = (const float*)d_in[10];
    const float* raw_b1  = (const float*)d_in[11];
    const float* raw_W2  = (const float*)d_in[12];
    const float* raw_b2  = (const float*)d_in[13];
    const float* alpha_W1 = (const float*)d_in[14];
    const float* alpha_b1 = (const float*)d_in[15];
    const float* alpha_W2 = (const float*)d_in[16];
    const float* alpha_b2 = (const float*)d_in[17];
    const float* out_W1  = (const float*)d_in[18];
    const float* out_b1  = (const float*)d_in[19];
    const float* out_W2  = (const float*)d_in[20];
    const float* out_b2  = (const float*)d_in[21];

    const size_t NBIG = (size_t)N * H;
    const size_t SSEG = (size_t)B * H;

    char* p = (char*)d_ws;
    ushort* cA  = (ushort*)p; p += NBIG * 2;   // comp bf16, later hid_raw
    ushort* cP  = (ushort*)p; p += NBIG * 2;   // prot bf16, later hid_alpha
    ushort* e1  = (ushort*)p; p += NBIG * 2;   // comp_emb bf16
    ushort* e2  = (ushort*)p; p += NBIG * 2;   // csup bf16, later raw bf16
    ushort* e3  = (ushort*)p; p += NBIG * 2;   // prot_emb bf16
    float* supe = (float*)p;  p += SSEG * 4;
    float* pool = (float*)p;  p += SSEG * 4;
    float* gr   = (float*)p;  p += SSEG * 4;
    float* ga   = (float*)p;  p += SSEG * 4;
    float* pre  = (float*)p;  p += (size_t)N * 4;
    ushort* WT1 = (ushort*)p; p += (size_t)512 * 256 * 2;  // [c_aff^T ; c_sup^T]
    ushort* WTp = (ushort*)p; p += (size_t)256 * 256 * 2;  // p_aff^T
    ushort* WT2 = (ushort*)p; p += (size_t)512 * 256 * 2;  // [raw_W1[0:256]^T ; alpha_W1[0:256]^T]
    ushort* WTr = (ushort*)p; p += (size_t)256 * 256 * 2;  // raw_W2^T
    int* sc = (int*)p; p += (size_t)(B + 1) * 4;
    int* sp = (int*)p; p += (size_t)(B + 1) * 4;
    if ((size_t)(p - (char*)d_ws) > ws_size) return;

    ushort* h1   = cA;   // hid_raw
    ushort* h2   = cP;   // hid_alpha
    ushort* rawb = e2;   // raw bf16

    float* out_vec   = (float*)d_out;
    float* out_alpha = out_vec + SSEG;
    float* out_aff   = out_alpha + N;

    dim3 blk(256);

    // 1. segment bounds + input casts + weight transposes
    seg_bounds_k<<<(2 * (B + 1) + 255) / 256, blk, 0, stream>>>(bc, bp, sc, sp, N, B);
    cast_bf_k<<<2048, blk, 0, stream>>>(comp, cA, NBIG / 4);
    cast_bf_k<<<2048, blk, 0, stream>>>(prot, cP, NBIG / 4);
    wt_cast_k<<<256, blk, 0, stream>>>(c_aff_W, WT1, H, H);
    wt_cast_k<<<256, blk, 0, stream>>>(c_sup_W, WT1 + 256 * 256, H, H);
    wt_cast_k<<<256, blk, 0, stream>>>(p_aff_W, WTp, H, H);
    wt_cast_k<<<256, blk, 0, stream>>>(raw_W1,   WT2, H, H);             // first 256 rows
    wt_cast_k<<<256, blk, 0, stream>>>(alpha_W1, WT2 + 256 * 256, H, H); // first 256 rows
    wt_cast_k<<<256, blk, 0, stream>>>(raw_W2, WTr, H, H);

    // 2. comp_emb | csup = leaky(comp @ [c_aff_W|c_sup_W] + bias)   [N,512] merged
    mgemm<true, false><<<dim3(N / 128, 4), blk, 0, stream>>>(
        cA, WT1, c_aff_b, c_sup_b, nullptr, nullptr, nullptr, e1, e2);
    // 3. prot_emb = leaky(prot @ p_aff_W + b)
    mgemm<true, false><<<dim3(N / 128, 2), blk, 0, stream>>>(
        cP, WTp, p_aff_b, nullptr, nullptr, nullptr, nullptr, e3, nullptr);
    // 4. segment pools (fp32 out)
    seg_reduce_bf<false><<<B, blk, 0, stream>>>(e2, sc, supe);
    seg_reduce_bf<true ><<<B, blk, 0, stream>>>(e3, sp, pool);
    // 5. gr/ga = supe@W1[256:512] + pool@W1[512:768] + b1  (small fp32 GEMMs)
    gemm64<false, false, true><<<dim3(B / 64, 4), blk, 0, stream>>>(supe, raw_W1 + H * H, pool,
        raw_W1 + 2 * H * H, raw_b1, nullptr, nullptr, gr, B);
    gemm64<false, false, true><<<dim3(B / 64, 4), blk, 0, stream>>>(supe, alpha_W1 + H * H, pool,
        alpha_W1 + 2 * H * H, alpha_b1, nullptr, nullptr, ga, B);
    // 6. hid_raw | hid_alpha = leaky(comp_emb @ [W1r|W1a] + G[bc[row]])  [N,512] merged
    mgemm<true, true><<<dim3(N / 128, 4), blk, 0, stream>>>(
        e1, WT2, nullptr, nullptr, gr, ga, bc, h1, h2);
    // 7. raw = hid_raw @ raw_W2 + b2
    mgemm<false, false><<<dim3(N / 128, 2), blk, 0, stream>>>(
        h1, WTr, raw_b2, nullptr, nullptr, nullptr, nullptr, rawb, nullptr);
    // 8. prealpha
    gemv_bf<<<N / 4, blk, 0, stream>>>(h2, alpha_W2, alpha_b2, pre);
    // 9. scatter softmax -> alpha
    seg_softmax_k<<<B, dim3(64), 0, stream>>>(pre, sc, out_alpha);
    // 10. vector
    seg_wsum_bf<<<B, blk, 0, stream>>>(rawb, out_alpha, sc, out_vec);
    // 11. affinity
    affinity_k<<<B, blk, 0, stream>>>(out_vec, out_W1, out_b1, out_W2, out_b2, out_aff);
}

// Round 3
// 1013.768 us; speedup vs baseline: 3.2485x; 1.1203x over previous
//
#include <hip/hip_runtime.h>
#include <cstddef>
#include <cstdint>

#define HDIM 256
#define BSEG 4096

typedef __bf16 bf16x8 __attribute__((ext_vector_type(8)));
typedef float f32x4 __attribute__((ext_vector_type(4)));

__device__ __forceinline__ float leaky(float x) { return x >= 0.f ? x : 0.1f * x; }

__device__ __forceinline__ float bf2f(ushort u) {
    return __builtin_bit_cast(float, (uint32_t)u << 16);
}
__device__ __forceinline__ ushort f2bf(float f) {  // RNE
    uint32_t x = __builtin_bit_cast(uint32_t, f);
    return (ushort)((x + 0x7fffu + ((x >> 16) & 1u)) >> 16);
}

// async global->LDS, 16 bytes per lane
__device__ __forceinline__ void gld16(const ushort* g, ushort* lds) {
    __builtin_amdgcn_global_load_lds(
        (const __attribute__((address_space(1))) uint32_t*)g,
        (__attribute__((address_space(3))) uint32_t*)lds, 16, 0, 0);
}

// ---------- segment bounds (batch arrays sorted) ----------
__global__ void seg_bounds_k(const int* __restrict__ bc, const int* __restrict__ bp,
                             int* __restrict__ sc, int* __restrict__ sp, int n, int nb)
{
    int t = blockIdx.x * blockDim.x + threadIdx.x;
    if (t >= 2 * (nb + 1)) return;
    bool isc = (t <= nb);
    const int* a = isc ? bc : bp;
    int v = isc ? t : t - (nb + 1);
    int lo = 0, hi = n;
    while (lo < hi) { int mid = (lo + hi) >> 1; if (a[mid] < v) lo = mid + 1; else hi = mid; }
    if (isc) sc[t] = lo; else sp[t - (nb + 1)] = lo;
}

// ---------- fp32 -> bf16 cast (vectorized) ----------
__global__ __launch_bounds__(256) void cast_bf_k(const float* __restrict__ in,
        ushort* __restrict__ out, long n4)
{
    long i = (long)blockIdx.x * blockDim.x + threadIdx.x;
    long stride = (long)gridDim.x * blockDim.x;
    for (; i < n4; i += stride) {
        float4 v = ((const float4*)in)[i];
        ushort4 o; o.x = f2bf(v.x); o.y = f2bf(v.y); o.z = f2bf(v.z); o.w = f2bf(v.w);
        ((ushort4*)out)[i] = o;
    }
}

// ---------- weight transpose + cast: WT[c*K + r] = bf16(W[r*NO + c]) ----------
__global__ __launch_bounds__(256) void wt_cast_k(const float* __restrict__ W,
        ushort* __restrict__ WT, int K, int NO)
{
    int i = blockIdx.x * 256 + threadIdx.x;
    if (i >= K * NO) return;
    int r = i / NO, c = i % NO;
    WT[(size_t)c * K + r] = f2bf(W[i]);
}

// ---------- bf16 MFMA GEMM (128x128 tile, BK=32, dbuf LDS, swizzled) ----------
// A:[M,256] bf16 row-major. BT:[NOtot,256] bf16 (weights pre-transposed).
// Output columns in halves of 256: half h uses bias_h / rt_h / out_h.
// YT = gridDim.y equivalent (col tiles), grid is 1-D with XCD-chunked swizzle.
template<bool LEAKYACT, bool ROWBIAS, int YT>
__global__ __launch_bounds__(256) void mgemm(
    const ushort* __restrict__ A, const ushort* __restrict__ BT,
    const float* __restrict__ bias0, const float* __restrict__ bias1,
    const float* __restrict__ rt0, const float* __restrict__ rt1,
    const int* __restrict__ idx,
    ushort* __restrict__ out0, ushort* __restrict__ out1)
{
    __shared__ __attribute__((aligned(16))) ushort As[2][128 * 32];
    __shared__ __attribute__((aligned(16))) ushort Bs[2][128 * 32];

    const int tid = threadIdx.x;

    // XCD-chunked tile swizzle: consecutive tiles (sharing an A panel) land on
    // the same XCD so A re-reads hit that XCD's L2.
    const uint nwg = gridDim.x;
    const uint orig = blockIdx.x;
    const uint swz = (orig & 7) * (nwg >> 3) + (orig >> 3);
    const int bx = (int)(swz / YT), by = (int)(swz % YT);
    const int row0 = bx * 128, col0 = by * 128;

    const int w = tid >> 6, l = tid & 63;
    const int wr = (w >> 1) * 64, wc = (w & 1) * 64;
    const int lr = l & 15, lt = l >> 4;

    // staging: lane handles (srow = tid>>2, slot = tid&3); source slot swizzled
    const int srow = tid >> 2;
    const int sslot = tid & 3;
    const int ssw = ((sslot ^ ((srow >> 1) & 3)) << 3);   // elems
    const ushort* Ab = A + (size_t)(row0 + srow) * HDIM + ssw;
    const ushort* Bb = BT + (size_t)(col0 + srow) * HDIM + ssw;

    // read-side swizzle (elem offset within 32-elem LDS row)
    const int sw_rd = ((lt ^ ((lr >> 1) & 3)) << 3);

    f32x4 acc[4][4] = {};

#define STAGE(buf, k0) do { \
        gld16(Ab + (k0),              &As[buf][tid * 8]); \
        gld16(Ab + 64 * HDIM + (k0),  &As[buf][2048 + tid * 8]); \
        gld16(Bb + (k0),              &Bs[buf][tid * 8]); \
        gld16(Bb + 64 * HDIM + (k0),  &Bs[buf][2048 + tid * 8]); \
    } while (0)

#define COMPUTE(buf) do { \
        bf16x8 af[4], bfv[4]; \
        _Pragma("unroll") \
        for (int m = 0; m < 4; ++m) \
            af[m] = *(const bf16x8*)&As[buf][(wr + m * 16 + lr) * 32 + sw_rd]; \
        _Pragma("unroll") \
        for (int n = 0; n < 4; ++n) \
            bfv[n] = *(const bf16x8*)&Bs[buf][(wc + n * 16 + lr) * 32 + sw_rd]; \
        _Pragma("unroll") \
        for (int m = 0; m < 4; ++m) \
            _Pragma("unroll") \
            for (int n = 0; n < 4; ++n) \
                acc[m][n] = __builtin_amdgcn_mfma_f32_16x16x32_bf16(bfv[n], af[m], acc[m][n], 0, 0, 0); \
    } while (0)

    STAGE(0, 0);
    __syncthreads();
    int cur = 0;
    #pragma unroll
    for (int t = 1; t < 8; ++t) {
        STAGE(cur ^ 1, t * 32);
        COMPUTE(cur);
        __syncthreads();
        cur ^= 1;
    }
    COMPUTE(cur);

#undef STAGE
#undef COMPUTE

    // Swapped operands => acc[m][n][e]: out_row = row0+wr+m*16+lr,
    // out_col = (col-in-half base) oc0 + n*16 + lt*4 + e  -> ushort4 stores.
    const int half = col0 >> 8;   // block-uniform
    const float* bias = half ? bias1 : bias0;
    const float* rtab = half ? rt1 : rt0;
    ushort* outp = half ? out1 : out0;
    const int oc0 = (col0 & 255) + wc + (lt << 2);

    #pragma unroll
    for (int m = 0; m < 4; ++m) {
        const int row = row0 + wr + m * 16 + lr;
        const float* rrow = nullptr;
        if (ROWBIAS) rrow = rtab + (size_t)idx[row] * HDIM;
        #pragma unroll
        for (int n = 0; n < 4; ++n) {
            const int c = oc0 + n * 16;
            float v0 = acc[m][n][0], v1 = acc[m][n][1], v2 = acc[m][n][2], v3 = acc[m][n][3];
            if (bias) {
                float4 b4 = *(const float4*)&bias[c];
                v0 += b4.x; v1 += b4.y; v2 += b4.z; v3 += b4.w;
            }
            if (ROWBIAS) {
                float4 r4 = *(const float4*)&rrow[c];
                v0 += r4.x; v1 += r4.y; v2 += r4.z; v3 += r4.w;
            }
            if (LEAKYACT) { v0 = leaky(v0); v1 = leaky(v1); v2 = leaky(v2); v3 = leaky(v3); }
            ushort4 o; o.x = f2bf(v0); o.y = f2bf(v1); o.z = f2bf(v2); o.w = f2bf(v3);
            *(ushort4*)&outp[(size_t)row * HDIM + c] = o;
        }
    }
}

// ---------- fp32 tiled GEMM (small dual [B,H] GEMMs) ----------
template<bool LEAKYACT, bool ROWBIAS, bool DUAL>
__global__ __launch_bounds__(256) void gemm64(
    const float* __restrict__ A, const float* __restrict__ W,
    const float* __restrict__ A2, const float* __restrict__ W2,
    const float* __restrict__ bias, const float* __restrict__ rowtab,
    const int* __restrict__ idx, float* __restrict__ C, int M)
{
    const int K = HDIM, NO = HDIM;
    __shared__ float As [16][68];
    __shared__ float Bs [16][68];
    __shared__ float As2[16][68];
    __shared__ float Bs2[16][68];

    const int tid = threadIdx.x;
    const int tx = tid & 15, ty = tid >> 4;
    const int row0 = blockIdx.x * 64, col0 = blockIdx.y * 64;

    const int lr = tid >> 2;
    const int lk = (tid & 3) << 2;
    const int bk = tid >> 4;
    const int bj = (tid & 15) << 2;

    float acc[4][4] = {};

    for (int k0 = 0; k0 < K; k0 += 16) {
        float4 a4 = *(const float4*)&A[(size_t)(row0 + lr) * K + k0 + lk];
        As[lk + 0][lr] = a4.x; As[lk + 1][lr] = a4.y;
        As[lk + 2][lr] = a4.z; As[lk + 3][lr] = a4.w;
        *(float4*)&Bs[bk][bj] = *(const float4*)&W[(size_t)(k0 + bk) * NO + col0 + bj];
        if (DUAL) {
            float4 c4 = *(const float4*)&A2[(size_t)(row0 + lr) * K + k0 + lk];
            As2[lk + 0][lr] = c4.x; As2[lk + 1][lr] = c4.y;
            As2[lk + 2][lr] = c4.z; As2[lk + 3][lr] = c4.w;
            *(float4*)&Bs2[bk][bj] = *(const float4*)&W2[(size_t)(k0 + bk) * NO + col0 + bj];
        }
        __syncthreads();
        #pragma unroll
        for (int kk = 0; kk < 16; ++kk) {
            float4 av = *(const float4*)&As[kk][ty << 2];
            float4 bv = *(const float4*)&Bs[kk][tx << 2];
            float a_[4] = {av.x, av.y, av.z, av.w};
            float b_[4] = {bv.x, bv.y, bv.z, bv.w};
            #pragma unroll
            for (int i = 0; i < 4; ++i)
                #pragma unroll
                for (int j = 0; j < 4; ++j)
                    acc[i][j] += a_[i] * b_[j];
            if (DUAL) {
                float4 av2 = *(const float4*)&As2[kk][ty << 2];
                float4 bv2 = *(const float4*)&Bs2[kk][tx << 2];
                float c_[4] = {av2.x, av2.y, av2.z, av2.w};
                float d_[4] = {bv2.x, bv2.y, bv2.z, bv2.w};
                #pragma unroll
                for (int i = 0; i < 4; ++i)
                    #pragma unroll
                    for (int j = 0; j < 4; ++j)
                        acc[i][j] += c_[i] * d_[j];
            }
        }
        __syncthreads();
    }

    #pragma unroll
    for (int i = 0; i < 4; ++i) {
        int row = row0 + (ty << 2) + i;
        const float* rt = nullptr;
        if (ROWBIAS) rt = &rowtab[(size_t)idx[row] * NO];
        float vv[4];
        #pragma unroll
        for (int j = 0; j < 4; ++j) {
            int col = col0 + (tx << 2) + j;
            float v = acc[i][j];
            if (bias) v += bias[col];
            if (ROWBIAS) v += rt[col];
            if (LEAKYACT) v = leaky(v);
            vv[j] = v;
        }
        float4 o; o.x = vv[0]; o.y = vv[1]; o.z = vv[2]; o.w = vv[3];
        *(float4*)&C[(size_t)row * NO + col0 + (tx << 2)] = o;
    }
}

// ---------- per-segment column reduce from bf16 input (sum or max) ----------
template<bool ISMAX>
__global__ __launch_bounds__(256) void seg_reduce_bf(const ushort* __restrict__ in,
        const int* __restrict__ starts, float* __restrict__ out)
{
    __shared__ float part[4][HDIM];
    int b = blockIdx.x, tid = threadIdx.x;
    int wid = tid >> 6, lane = tid & 63;
    int s = starts[b], e = starts[b + 1];
    float a0 = ISMAX ? -INFINITY : 0.f, a1 = a0, a2 = a0, a3 = a0;
    for (int i = s + wid; i < e; i += 4) {
        ushort4 v = *(const ushort4*)&in[(size_t)i * HDIM + lane * 4];
        float f0 = bf2f(v.x), f1 = bf2f(v.y), f2 = bf2f(v.z), f3 = bf2f(v.w);
        if (ISMAX) { a0 = fmaxf(a0, f0); a1 = fmaxf(a1, f1); a2 = fmaxf(a2, f2); a3 = fmaxf(a3, f3); }
        else       { a0 += f0; a1 += f1; a2 += f2; a3 += f3; }
    }
    part[wid][lane * 4 + 0] = a0; part[wid][lane * 4 + 1] = a1;
    part[wid][lane * 4 + 2] = a2; part[wid][lane * 4 + 3] = a3;
    __syncthreads();
    float r = ISMAX ? fmaxf(fmaxf(part[0][tid], part[1][tid]), fmaxf(part[2][tid], part[3][tid]))
                    : (part[0][tid] + part[1][tid] + part[2][tid] + part[3][tid]);
    out[(size_t)b * HDIM + tid] = r;
}

// ---------- prealpha GEMV from bf16 hidden ----------
__global__ __launch_bounds__(256) void gemv_bf(const ushort* __restrict__ Hd,
        const float* __restrict__ w, const float* __restrict__ bptr,
        float* __restrict__ out)
{
    int lane = threadIdx.x & 63, wid = threadIdx.x >> 6;
    int row = blockIdx.x * 4 + wid;
    ushort4 h4 = *(const ushort4*)&Hd[(size_t)row * HDIM + lane * 4];
    float4 wv = *(const float4*)&w[lane * 4];
    float p = bf2f(h4.x) * wv.x + bf2f(h4.y) * wv.y + bf2f(h4.z) * wv.z + bf2f(h4.w) * wv.w;
    #pragma unroll
    for (int off = 32; off; off >>= 1) p += __shfl_down(p, off);
    if (lane == 0) out[row] = p + bptr[0];
}

// ---------- scatter softmax over contiguous segments ----------
__global__ __launch_bounds__(64) void seg_softmax_k(const float* __restrict__ pre,
        const int* __restrict__ starts, float* __restrict__ alpha)
{
    int b = blockIdx.x, lane = threadIdx.x;
    int s = starts[b], e = starts[b + 1];
    float m = -INFINITY;
    for (int i = s + lane; i < e; i += 64) m = fmaxf(m, pre[i]);
    #pragma unroll
    for (int off = 32; off; off >>= 1) m = fmaxf(m, __shfl_xor(m, off));
    float sum = 0.f;
    for (int i = s + lane; i < e; i += 64) sum += expf(pre[i] - m);
    #pragma unroll
    for (int off = 32; off; off >>= 1) sum += __shfl_xor(sum, off);
    sum += 1e-6f;
    for (int i = s + lane; i < e; i += 64) alpha[i] = expf(pre[i] - m) / sum;
}

// ---------- vector[b,:] = sum raw[i,:]*alpha[i], raw in bf16 ----------
__global__ __launch_bounds__(256) void seg_wsum_bf(const ushort* __restrict__ raw,
        const float* __restrict__ alpha, const int* __restrict__ starts,
        float* __restrict__ vec)
{
    __shared__ float part[4][HDIM];
    int b = blockIdx.x, tid = threadIdx.x;
    int wid = tid >> 6, lane = tid & 63;
    int s = starts[b], e = starts[b + 1];
    float a0 = 0.f, a1 = 0.f, a2 = 0.f, a3 = 0.f;
    for (int i = s + wid; i < e; i += 4) {
        float al = alpha[i];
        ushort4 v = *(const ushort4*)&raw[(size_t)i * HDIM + lane * 4];
        a0 += bf2f(v.x) * al; a1 += bf2f(v.y) * al; a2 += bf2f(v.z) * al; a3 += bf2f(v.w) * al;
    }
    part[wid][lane * 4 + 0] = a0; part[wid][lane * 4 + 1] = a1;
    part[wid][lane * 4 + 2] = a2; part[wid][lane * 4 + 3] = a3;
    __syncthreads();
    vec[(size_t)b * HDIM + tid] = part[0][tid] + part[1][tid] + part[2][tid] + part[3][tid];
}

// ---------- affinity head ----------
__global__ __launch_bounds__(256) void affinity_k(const float* __restrict__ vec,
        const float* __restrict__ W1, const float* __restrict__ b1,
        const float* __restrict__ W2, const float* __restrict__ b2,
        float* __restrict__ out)
{
    __shared__ float v[HDIM];
    __shared__ float red[4];
    int b = blockIdx.x, t = threadIdx.x;
    v[t] = vec[(size_t)b * HDIM + t];
    __syncthreads();
    float h = 0.f;
    #pragma unroll 8
    for (int k = 0; k < HDIM; ++k) h += v[k] * W1[(size_t)k * HDIM + t];
    h += b1[t];
    h = leaky(h);
    float p = h * W2[t];
    #pragma unroll
    for (int off = 32; off; off >>= 1) p += __shfl_down(p, off);
    int lane = t & 63, wid = t >> 6;
    if (lane == 0) red[wid] = p;
    __syncthreads();
    if (t == 0) out[b] = red[0] + red[1] + red[2] + red[3] + b2[0];
}

extern "C" void kernel_launch(void* const* d_in, const int* in_sizes, int n_in,
                              void* d_out, int out_size, void* d_ws, size_t ws_size,
                              hipStream_t stream)
{
    const int N = in_sizes[2];
    const int H = HDIM;
    const int B = BSEG;

    const float* comp   = (const float*)d_in[0];
    const float* prot   = (const float*)d_in[1];
    const int*   bc     = (const int*)d_in[2];
    const int*   bp     = (const int*)d_in[3];
    const float* c_aff_W = (const float*)d_in[4];
    const float* c_aff_b = (const float*)d_in[5];
    const float* c_sup_W = (const float*)d_in[6];
    const float* c_sup_b = (const float*)d_in[7];
    const float* p_aff_W = (const float*)d_in[8];
    const float* p_aff_b = (const float*)d_in[9];
    const float* raw_W1  = (const float*)d_in[10];
    const float* raw_b1  = (const float*)d_in[11];
    const float* raw_W2  = (const float*)d_in[12];
    const float* raw_b2  = (const float*)d_in[13];
    const float* alpha_W1 = (const float*)d_in[14];
    const float* alpha_b1 = (const float*)d_in[15];
    const float* alpha_W2 = (const float*)d_in[16];
    const float* alpha_b2 = (const float*)d_in[17];
    const float* out_W1  = (const float*)d_in[18];
    const float* out_b1  = (const float*)d_in[19];
    const float* out_W2  = (const float*)d_in[20];
    const float* out_b2  = (const float*)d_in[21];

    const size_t NBIG = (size_t)N * H;
    const size_t SSEG = (size_t)B * H;

    char* p = (char*)d_ws;
    ushort* cA  = (ushort*)p; p += NBIG * 2;   // comp bf16, later hid_raw
    ushort* cP  = (ushort*)p; p += NBIG * 2;   // prot bf16, later hid_alpha
    ushort* e1  = (ushort*)p; p += NBIG * 2;   // comp_emb bf16
    ushort* e2  = (ushort*)p; p += NBIG * 2;   // csup bf16, later raw bf16
    ushort* e3  = (ushort*)p; p += NBIG * 2;   // prot_emb bf16
    float* supe = (float*)p;  p += SSEG * 4;
    float* pool = (float*)p;  p += SSEG * 4;
    float* gr   = (float*)p;  p += SSEG * 4;
    float* ga   = (float*)p;  p += SSEG * 4;
    float* pre  = (float*)p;  p += (size_t)N * 4;
    ushort* WT1 = (ushort*)p; p += (size_t)512 * 256 * 2;  // [c_aff^T ; c_sup^T]
    ushort* WTp = (ushort*)p; p += (size_t)256 * 256 * 2;  // p_aff^T
    ushort* WT2 = (ushort*)p; p += (size_t)512 * 256 * 2;  // [raw_W1[0:256]^T ; alpha_W1[0:256]^T]
    ushort* WTr = (ushort*)p; p += (size_t)256 * 256 * 2;  // raw_W2^T
    int* sc = (int*)p; p += (size_t)(B + 1) * 4;
    int* sp = (int*)p; p += (size_t)(B + 1) * 4;
    if ((size_t)(p - (char*)d_ws) > ws_size) return;

    ushort* h1   = cA;   // hid_raw
    ushort* h2   = cP;   // hid_alpha
    ushort* rawb = e2;   // raw bf16

    float* out_vec   = (float*)d_out;
    float* out_alpha = out_vec + SSEG;
    float* out_aff   = out_alpha + N;

    dim3 blk(256);

    // 1. segment bounds + input casts + weight transposes
    seg_bounds_k<<<(2 * (B + 1) + 255) / 256, blk, 0, stream>>>(bc, bp, sc, sp, N, B);
    cast_bf_k<<<2048, blk, 0, stream>>>(comp, cA, NBIG / 4);
    cast_bf_k<<<2048, blk, 0, stream>>>(prot, cP, NBIG / 4);
    wt_cast_k<<<256, blk, 0, stream>>>(c_aff_W, WT1, H, H);
    wt_cast_k<<<256, blk, 0, stream>>>(c_sup_W, WT1 + 256 * 256, H, H);
    wt_cast_k<<<256, blk, 0, stream>>>(p_aff_W, WTp, H, H);
    wt_cast_k<<<256, blk, 0, stream>>>(raw_W1,   WT2, H, H);
    wt_cast_k<<<256, blk, 0, stream>>>(alpha_W1, WT2 + 256 * 256, H, H);
    wt_cast_k<<<256, blk, 0, stream>>>(raw_W2, WTr, H, H);

    // 2. comp_emb | csup = leaky(comp @ [c_aff_W|c_sup_W] + bias)   [N,512] merged
    mgemm<true, false, 4><<<dim3(N / 128 * 4), blk, 0, stream>>>(
        cA, WT1, c_aff_b, c_sup_b, nullptr, nullptr, nullptr, e1, e2);
    // 3. prot_emb = leaky(prot @ p_aff_W + b)
    mgemm<true, false, 2><<<dim3(N / 128 * 2), blk, 0, stream>>>(
        cP, WTp, p_aff_b, nullptr, nullptr, nullptr, nullptr, e3, nullptr);
    // 4. segment pools (fp32 out)
    seg_reduce_bf<false><<<B, blk, 0, stream>>>(e2, sc, supe);
    seg_reduce_bf<true ><<<B, blk, 0, stream>>>(e3, sp, pool);
    // 5. gr/ga = supe@W1[256:512] + pool@W1[512:768] + b1  (small fp32 GEMMs)
    gemm64<false, false, true><<<dim3(B / 64, 4), blk, 0, stream>>>(supe, raw_W1 + H * H, pool,
        raw_W1 + 2 * H * H, raw_b1, nullptr, nullptr, gr, B);
    gemm64<false, false, true><<<dim3(B / 64, 4), blk, 0, stream>>>(supe, alpha_W1 + H * H, pool,
        alpha_W1 + 2 * H * H, alpha_b1, nullptr, nullptr, ga, B);
    // 6. hid_raw | hid_alpha = leaky(comp_emb @ [W1r|W1a] + G[bc[row]])  [N,512] merged
    mgemm<true, true, 4><<<dim3(N / 128 * 4), blk, 0, stream>>>(
        e1, WT2, nullptr, nullptr, gr, ga, bc, h1, h2);
    // 7. raw = hid_raw @ raw_W2 + b2
    mgemm<false, false, 2><<<dim3(N / 128 * 2), blk, 0, stream>>>(
        h1, WTr, raw_b2, nullptr, nullptr, nullptr, nullptr, rawb, nullptr);
    // 8. prealpha
    gemv_bf<<<N / 4, blk, 0, stream>>>(h2, alpha_W2, alpha_b2, pre);
    // 9. scatter softmax -> alpha
    seg_softmax_k<<<B, dim3(64), 0, stream>>>(pre, sc, out_alpha);
    // 10. vector
    seg_wsum_bf<<<B, blk, 0, stream>>>(rawb, out_alpha, sc, out_vec);
    // 11. affinity
    affinity_k<<<B, blk, 0, stream>>>(out_vec, out_W1, out_b1, out_W2, out_b2, out_aff);
}